// Round 14
// baseline (218.147 us; speedup 1.0000x reference)
//
#include <hip/hip_runtime.h>
#include <hip/hip_bf16.h>

#define Nn 10000
#define Ee 160000
#define Hid 256
#define Cc 64

typedef unsigned int uint32;
typedef unsigned short ushort16;
typedef __attribute__((ext_vector_type(8))) short short8;
typedef __attribute__((ext_vector_type(4))) float float4v;

__device__ inline float2 bfpair(uint32 u) {
    float2 r;
    r.x = __uint_as_float(u << 16);
    r.y = __uint_as_float(u & 0xffff0000u);
    return r;
}
__device__ inline ushort16 f2bf(float f) {
    __hip_bfloat16 h = __float2bfloat16(f);
    union { __hip_bfloat16 h; ushort16 u; } cv;
    cv.h = h;
    return cv.u;
}
__device__ inline uint32 packbf(float a, float b) {
    return (uint32)f2bf(a) | ((uint32)f2bf(b) << 16);
}

// ---- init: node arrays + acc/done (MUST complete before any atomics) -----------
__global__ __launch_bounds__(256) void init_kernel(float* deg, float* degrow,
                                                   int* cnt, int* cursor, float* acc) {
    int i = blockIdx.x * 256 + threadIdx.x;
    if (i < Nn) { deg[i] = 1.0f; degrow[i] = 0.0f; cnt[i] = 0; cursor[i] = 0; }
    if (blockIdx.x == 0 && threadIdx.x < 132) acc[threadIdx.x] = 0.0f;  // 130 = done ctr
}

// ---- bigprep: x->bf16 + W fragments + edge convert/stats (after init) ----------
__global__ __launch_bounds__(256) void bigprep_kernel(const void* ei,
                                                      const float* __restrict__ ea,
                                                      const float* __restrict__ x,
                                                      const float* __restrict__ W1,
                                                      const float* __restrict__ W2,
                                                      const float* __restrict__ Wm,
                                                      uint32* __restrict__ xb,
                                                      ushort16* __restrict__ w1f,
                                                      ushort16* __restrict__ w2f,
                                                      ushort16* __restrict__ wmf,
                                                      int* row32, int* col32,
                                                      float* deg, float* degrow,
                                                      int* cnt, float* g_sum_ea) {
    int b = blockIdx.x, t = threadIdx.x;
    if (b < 2500) {                                     // x: 640000 bf16 pairs
        int i = b * 256 + t;
        float2 v = *(const float2*)(x + 2 * (size_t)i);
        xb[i] = packbf(v.x, v.y);
    } else if (b < 2516) {                              // W1 frags: KT=4, NT=16
        int idx = (b - 2500) * 256 + t;
        int l = idx & 63, nt = (idx >> 6) & 15, kt = idx >> 10;
        int k0 = kt * 32 + (l >> 4) * 8, c = nt * 16 + (l & 15);
#pragma unroll
        for (int j = 0; j < 8; j++) w1f[idx * 8 + j] = f2bf(W1[(size_t)(k0 + j) * Hid + c]);
    } else if (b < 2548) {                              // W2 frags: KT=8, NT=16
        int idx = (b - 2516) * 256 + t;
        int l = idx & 63, nt = (idx >> 6) & 15, kt = idx >> 10;
        int k0 = kt * 32 + (l >> 4) * 8, c = nt * 16 + (l & 15);
#pragma unroll
        for (int j = 0; j < 8; j++) w2f[idx * 8 + j] = f2bf(W2[(size_t)(k0 + j) * Hid + c]);
    } else if (b < 2556) {                              // Wm frags: KT=8, NT=4
        int idx = (b - 2548) * 256 + t;
        int l = idx & 63, nt = (idx >> 6) & 3, kt = idx >> 8;
        int k0 = kt * 32 + (l >> 4) * 8, c = nt * 16 + (l & 15);
#pragma unroll
        for (int j = 0; j < 8; j++) wmf[idx * 8 + j] = f2bf(Wm[(size_t)(k0 + j) * Cc + c]);
    } else {                                            // edges: convert + stats
        __shared__ int any;
        if (t == 0) any = 0;
        __syncthreads();
        const int* w = (const int*)ei;
        for (int j = t; j < 1024; j += 256)
            if (w[2 * j + 1] != 0) { atomicOr(&any, 1); break; }
        __syncthreads();
        int is64 = (any == 0);
        int e = (b - 2556) * 256 + t;
        float v = 0.0f;
        if (e < Ee) {
            int r, c;
            if (is64) {
                r = (int)((const long long*)ei)[e];
                c = (int)((const long long*)ei)[Ee + e];
            } else {
                r = ((const int*)ei)[e];
                c = ((const int*)ei)[Ee + e];
            }
            row32[e] = r;
            col32[e] = c;
            float wv = ea[e];
            v = wv;
            atomicAdd(&deg[c], wv);
            atomicAdd(&degrow[r], wv);
            atomicAdd(&cnt[c], 1);
        }
        for (int o = 32; o; o >>= 1) v += __shfl_xor(v, o);
        __shared__ float sred[4];
        if ((t & 63) == 0) sred[t >> 6] = v;
        __syncthreads();
        if (t == 0) atomicAdd(g_sum_ea, sred[0] + sred[1] + sred[2] + sred[3]);
    }
}

// ---- scan + dinv + degree-sorted permutation (counting sort, 64 bins) ----------
__global__ __launch_bounds__(1024) void scan_dinv_sort_kernel(const int* cnt, int* offs,
                                                              const float* deg, float* dinv,
                                                              int* perm) {
    int t = threadIdx.x;
    for (int i = t; i < Nn; i += 1024) dinv[i] = rsqrtf(deg[i]);
    int st = t * 10;
    int pre[10];
    int s = 0;
#pragma unroll
    for (int j = 0; j < 10; j++) {
        int i = st + j;
        int v = (i < Nn) ? cnt[i] : 0;
        pre[j] = s;
        s += v;
    }
    int lane = t & 63, w = t >> 6;
    __shared__ int wsum[16];
    __shared__ int hist[64];
    __shared__ int binbase[64];
    if (t < 64) hist[t] = 0;
    int ps = s;
    for (int d = 1; d < 64; d <<= 1) {
        int u = __shfl_up(ps, d);
        if (lane >= d) ps += u;
    }
    if (lane == 63) wsum[w] = ps;
    __syncthreads();
    if (w == 0 && lane < 16) {
        int v = wsum[lane];
        for (int d = 1; d < 16; d <<= 1) {
            int u = __shfl_up(v, d);
            if (lane >= d) v += u;
        }
        wsum[lane] = v;
    }
    __syncthreads();
    int base = (w > 0 ? wsum[w - 1] : 0) + ps - s;
#pragma unroll
    for (int j = 0; j < 10; j++) {
        int i = st + j;
        if (i < Nn) offs[i] = base + pre[j];
    }
    if (t == 1023) offs[Nn] = wsum[15];
    // counting sort by degree (bin = min(deg,63))
#pragma unroll
    for (int j = 0; j < 10; j++) {
        int i = st + j;
        if (i < Nn) atomicAdd(&hist[min(cnt[i], 63)], 1);
    }
    __syncthreads();
    if (w == 0) {            // exclusive prefix of 64 bins in wave 0
        int v = hist[lane];
        int s2 = v;
        for (int d = 1; d < 64; d <<= 1) {
            int u = __shfl_up(s2, d);
            if (lane >= d) s2 += u;
        }
        binbase[lane] = s2 - v;
        hist[lane] = 0;      // reuse as cursor
    }
    __syncthreads();
#pragma unroll
    for (int j = 0; j < 10; j++) {
        int i = st + j;
        if (i < Nn) {
            int bk = min(cnt[i], 63);
            int slot = binbase[bk] + atomicAdd(&hist[bk], 1);
            perm[slot] = i;
        }
    }
}

// ---------------- fill CSC as 16B records {r, norm, ea, 0} ----------------------
__global__ __launch_bounds__(256) void fill_kernel(const int* __restrict__ row,
                                                   const int* __restrict__ col,
                                                   const float* __restrict__ ew,
                                                   const float* __restrict__ dinv,
                                                   const int* __restrict__ offs, int* cursor,
                                                   uint4* __restrict__ meta, int E) {
    int e = blockIdx.x * 256 + threadIdx.x;
    if (e >= E) return;
    int r = row[e], c = col[e];
    int slot = offs[c] + atomicAdd(&cursor[c], 1);
    float w = ew[e];
    uint4 m;
    m.x = (uint32)r;
    m.y = __float_as_uint(dinv[r] * w * dinv[c]);
    m.z = __float_as_uint(w);
    m.w = 0;
    meta[slot] = m;
}

// ---- agg single plane: 16 lanes/node, uint4 gathers, degree-sorted -------------
__global__ __launch_bounds__(256) void agg16_kernel(const uint4* __restrict__ src,
                                                    const float* __restrict__ dinv,
                                                    const int* __restrict__ offs,
                                                    const uint4* __restrict__ meta,
                                                    const int* __restrict__ perm,
                                                    uint4* __restrict__ dst) {
    int g = threadIdx.x >> 4, l = threadIdx.x & 15;
    int i = perm[blockIdx.x * 16 + g];
    float di = dinv[i];
    float w2 = di * di;
    uint4 su = src[(size_t)i * 16 + l];
    float a0, a1, a2, a3, a4, a5, a6, a7;
    {
        float2 p0 = bfpair(su.x), p1 = bfpair(su.y), p2 = bfpair(su.z), p3 = bfpair(su.w);
        a0 = w2 * p0.x; a1 = w2 * p0.y; a2 = w2 * p1.x; a3 = w2 * p1.y;
        a4 = w2 * p2.x; a5 = w2 * p2.y; a6 = w2 * p3.x; a7 = w2 * p3.y;
    }
#define ACC8(u, wgt) { \
        float2 p0 = bfpair(u.x), p1 = bfpair(u.y), p2 = bfpair(u.z), p3 = bfpair(u.w); \
        a0 = fmaf(wgt, p0.x, a0); a1 = fmaf(wgt, p0.y, a1); \
        a2 = fmaf(wgt, p1.x, a2); a3 = fmaf(wgt, p1.y, a3); \
        a4 = fmaf(wgt, p2.x, a4); a5 = fmaf(wgt, p2.y, a5); \
        a6 = fmaf(wgt, p3.x, a6); a7 = fmaf(wgt, p3.y, a7); }
    int e0 = offs[i], e1 = offs[i + 1];
    int k = e0;
    for (; k + 4 <= e1; k += 4) {
        uint4 m0 = meta[k], m1 = meta[k + 1], m2 = meta[k + 2], m3 = meta[k + 3];
        uint4 u0 = src[(size_t)m0.x * 16 + l];
        uint4 u1 = src[(size_t)m1.x * 16 + l];
        uint4 u2 = src[(size_t)m2.x * 16 + l];
        uint4 u3 = src[(size_t)m3.x * 16 + l];
        ACC8(u0, __uint_as_float(m0.y));
        ACC8(u1, __uint_as_float(m1.y));
        ACC8(u2, __uint_as_float(m2.y));
        ACC8(u3, __uint_as_float(m3.y));
    }
    for (; k < e1; k++) {
        uint4 m0 = meta[k];
        uint4 u0 = src[(size_t)m0.x * 16 + l];
        ACC8(u0, __uint_as_float(m0.y));
    }
#undef ACC8
    uint4 o;
    o.x = packbf(a0, a1);
    o.y = packbf(a2, a3);
    o.z = packbf(a4, a5);
    o.w = packbf(a6, a7);
    dst[(size_t)i * 16 + l] = o;
}

// ---- agg DUAL plane (layer 2), degree-sorted -----------------------------------
__global__ __launch_bounds__(256) void agg16x2_kernel(const uint4* __restrict__ srcLo,
                                                      const uint4* __restrict__ srcHi,
                                                      const float* __restrict__ dinv,
                                                      const int* __restrict__ offs,
                                                      const uint4* __restrict__ meta,
                                                      const int* __restrict__ perm,
                                                      uint4* __restrict__ dst) {
    int g = threadIdx.x >> 4, l = threadIdx.x & 15;
    int i = perm[blockIdx.x * 16 + g];
    float di = dinv[i];
    float w2 = di * di;
    uint4 slo = srcLo[(size_t)i * 16 + l];
    uint4 shi = srcHi[(size_t)i * 16 + l];
    float a0, a1, a2, a3, a4, a5, a6, a7;
    float b0, b1, b2, b3, b4, b5, b6, b7;
    {
        float2 p0 = bfpair(slo.x), p1 = bfpair(slo.y), p2 = bfpair(slo.z), p3 = bfpair(slo.w);
        a0 = w2 * p0.x; a1 = w2 * p0.y; a2 = w2 * p1.x; a3 = w2 * p1.y;
        a4 = w2 * p2.x; a5 = w2 * p2.y; a6 = w2 * p3.x; a7 = w2 * p3.y;
        float2 q0 = bfpair(shi.x), q1 = bfpair(shi.y), q2 = bfpair(shi.z), q3 = bfpair(shi.w);
        b0 = w2 * q0.x; b1 = w2 * q0.y; b2 = w2 * q1.x; b3 = w2 * q1.y;
        b4 = w2 * q2.x; b5 = w2 * q2.y; b6 = w2 * q3.x; b7 = w2 * q3.y;
    }
#define ACCLO(u, wgt) { \
        float2 p0 = bfpair(u.x), p1 = bfpair(u.y), p2 = bfpair(u.z), p3 = bfpair(u.w); \
        a0 = fmaf(wgt, p0.x, a0); a1 = fmaf(wgt, p0.y, a1); \
        a2 = fmaf(wgt, p1.x, a2); a3 = fmaf(wgt, p1.y, a3); \
        a4 = fmaf(wgt, p2.x, a4); a5 = fmaf(wgt, p2.y, a5); \
        a6 = fmaf(wgt, p3.x, a6); a7 = fmaf(wgt, p3.y, a7); }
#define ACCHI(u, wgt) { \
        float2 p0 = bfpair(u.x), p1 = bfpair(u.y), p2 = bfpair(u.z), p3 = bfpair(u.w); \
        b0 = fmaf(wgt, p0.x, b0); b1 = fmaf(wgt, p0.y, b1); \
        b2 = fmaf(wgt, p1.x, b2); b3 = fmaf(wgt, p1.y, b3); \
        b4 = fmaf(wgt, p2.x, b4); b5 = fmaf(wgt, p2.y, b5); \
        b6 = fmaf(wgt, p3.x, b6); b7 = fmaf(wgt, p3.y, b7); }
    int e0 = offs[i], e1 = offs[i + 1];
    int k = e0;
    for (; k + 4 <= e1; k += 4) {
        uint4 m0 = meta[k], m1 = meta[k + 1], m2 = meta[k + 2], m3 = meta[k + 3];
        uint4 lo0 = srcLo[(size_t)m0.x * 16 + l];
        uint4 lo1 = srcLo[(size_t)m1.x * 16 + l];
        uint4 lo2 = srcLo[(size_t)m2.x * 16 + l];
        uint4 lo3 = srcLo[(size_t)m3.x * 16 + l];
        uint4 hi0 = srcHi[(size_t)m0.x * 16 + l];
        uint4 hi1 = srcHi[(size_t)m1.x * 16 + l];
        uint4 hi2 = srcHi[(size_t)m2.x * 16 + l];
        uint4 hi3 = srcHi[(size_t)m3.x * 16 + l];
        float w0 = __uint_as_float(m0.y), w1 = __uint_as_float(m1.y);
        float w2_ = __uint_as_float(m2.y), w3 = __uint_as_float(m3.y);
        ACCLO(lo0, w0); ACCHI(hi0, w0);
        ACCLO(lo1, w1); ACCHI(hi1, w1);
        ACCLO(lo2, w2_); ACCHI(hi2, w2_);
        ACCLO(lo3, w3); ACCHI(hi3, w3);
    }
    for (; k < e1; k++) {
        uint4 m0 = meta[k];
        uint4 lo0 = srcLo[(size_t)m0.x * 16 + l];
        uint4 hi0 = srcHi[(size_t)m0.x * 16 + l];
        float w0 = __uint_as_float(m0.y);
        ACCLO(lo0, w0); ACCHI(hi0, w0);
    }
#undef ACCLO
#undef ACCHI
    uint4 o;
    o.x = packbf(a0, a1);
    o.y = packbf(a2, a3);
    o.z = packbf(a4, a5);
    o.w = packbf(a6, a7);
    dst[(size_t)i * 32 + l] = o;
    o.x = packbf(b0, b1);
    o.y = packbf(b2, b3);
    o.z = packbf(b4, b5);
    o.w = packbf(b6, b7);
    dst[(size_t)i * 32 + 16 + l] = o;
}

// ---------------- gemm1: C = relu(A[M,128]bf16 @ W1 + b1) -> two planes ---------
__global__ __launch_bounds__(256) void gemm1_kernel(const ushort16* __restrict__ A,
                                                    const short8* __restrict__ wfrag,
                                                    const float* __restrict__ bias,
                                                    uint32* __restrict__ Plo,
                                                    uint32* __restrict__ Phi) {
    constexpr int KT = 4;
    int wave = threadIdx.x >> 6, lane = threadIdx.x & 63;
    int quad = lane >> 4, l4 = lane & 15;
    int rowbase = blockIdx.x * 16;
    int n0 = wave * 4;
    float4v acc[4];
#pragma unroll
    for (int n = 0; n < 4; n++) acc[n] = (float4v){0.f, 0.f, 0.f, 0.f};
    const short8* arow = (const short8*)(A + (size_t)(rowbase + l4) * 128 + quad * 8);
#pragma unroll
    for (int t = 0; t < KT; t++) {
        short8 a = arow[t * 4];
        const short8* bt = wfrag + ((size_t)t * 16 + n0) * 64 + lane;
#pragma unroll
        for (int n = 0; n < 4; n++)
            acc[n] = __builtin_amdgcn_mfma_f32_16x16x32_bf16(a, bt[n * 64], acc[n], 0, 0, 0);
    }
#pragma unroll
    for (int n = 0; n < 4; n++) {
        int col = (n0 + n) * 16 + l4;
        float bv = bias[col];
#pragma unroll
        for (int r = 0; r < 4; r++) {
            float v = fmaxf(acc[n][r] + bv, 0.0f);
            float v2 = __shfl_xor(v, 1);
            if ((l4 & 1) == 0) {
                int rowi = rowbase + quad * 4 + r;
                int pi = col >> 1;
                uint32 val = packbf(v, v2);
                uint32* P = (pi < 64) ? Plo : Phi;
                P[(size_t)rowi * 64 + (pi & 63)] = val;
            }
        }
    }
}

// ---- fused gemm2 + softmax (R13-proven) ----------------------------------------
__global__ __launch_bounds__(256) void gemm2_softmax_kernel(
    const ushort16* __restrict__ A, const short8* __restrict__ w2f,
    const float* __restrict__ b2, const short8* __restrict__ wmf,
    const float* __restrict__ bm, const float* __restrict__ degrow,
    float* __restrict__ s_out, uint32* __restrict__ sb, float* __restrict__ acc) {
    __shared__ uint32 h2s[16][132];
    __shared__ float Lw[4][16][65];
    int t = threadIdx.x;
    int wave = t >> 6, lane = t & 63;
    int quad = lane >> 4, l4 = lane & 15;
    int rowbase = blockIdx.x * 16;
    float4v acc4[4];
#pragma unroll
    for (int n = 0; n < 4; n++) acc4[n] = (float4v){0.f, 0.f, 0.f, 0.f};
    const short8* arow = (const short8*)(A + (size_t)(rowbase + l4) * Hid + quad * 8);
#pragma unroll
    for (int tt = 0; tt < 8; tt++) {
        short8 a = arow[tt * 4];
        const short8* bt = w2f + ((size_t)tt * 16 + wave * 4) * 64 + lane;
#pragma unroll
        for (int n = 0; n < 4; n++)
            acc4[n] = __builtin_amdgcn_mfma_f32_16x16x32_bf16(a, bt[n * 64], acc4[n], 0, 0, 0);
    }
#pragma unroll
    for (int n = 0; n < 4; n++) {
        int col = (wave * 4 + n) * 16 + l4;
        float bv = b2[col];
#pragma unroll
        for (int r = 0; r < 4; r++) {
            float v = fmaxf(acc4[n][r] + bv, 0.0f);
            float v2 = __shfl_xor(v, 1);
            if ((l4 & 1) == 0) h2s[quad * 4 + r][col >> 1] = packbf(v, v2);
        }
    }
    __syncthreads();
    float4v lg[4];
#pragma unroll
    for (int n = 0; n < 4; n++) lg[n] = (float4v){0.f, 0.f, 0.f, 0.f};
#pragma unroll
    for (int tt = 0; tt < 2; tt++) {
        int kt = wave * 2 + tt;
        short8 a = *(const short8*)&h2s[l4][kt * 16 + quad * 4];
        const short8* bt = wmf + ((size_t)kt * 4) * 64 + lane;
#pragma unroll
        for (int n = 0; n < 4; n++)
            lg[n] = __builtin_amdgcn_mfma_f32_16x16x32_bf16(a, bt[n * 64], lg[n], 0, 0, 0);
    }
#pragma unroll
    for (int n = 0; n < 4; n++)
#pragma unroll
        for (int r = 0; r < 4; r++)
            Lw[wave][quad * 4 + r][n * 16 + l4] = lg[n][r];
    __syncthreads();
    if (wave == 0) {
        float pc = 0.0f, pa = 0.0f;
        for (int r = 0; r < 16; r++) {
            float v = bm[lane] + Lw[0][r][lane] + Lw[1][r][lane] + Lw[2][r][lane]
                    + Lw[3][r][lane];
            float mx = v;
            for (int o = 32; o; o >>= 1) mx = fmaxf(mx, __shfl_xor(mx, o));
            float e = __expf(v - mx);
            float ss = e;
            for (int o = 32; o; o >>= 1) ss += __shfl_xor(ss, o);
            float sv = e / ss;
            int rowi = rowbase + r;
            s_out[(size_t)rowi * Cc + lane] = sv;
            float sv2 = __shfl_xor(sv, 1);
            if ((lane & 1) == 0) sb[(size_t)rowi * 32 + (lane >> 1)] = packbf(sv, sv2);
            pc += sv;
            pa += sv * degrow[rowi];
        }
        atomicAdd(&acc[lane], pc);
        atomicAdd(&acc[64 + lane], pa);
    }
}

// ---- trace (degree-sorted) + last-block final scalars --------------------------
__global__ __launch_bounds__(256) void trace16_final_kernel(const int* __restrict__ offs,
                                                            const uint4* __restrict__ meta,
                                                            const uint2* __restrict__ s2,
                                                            const int* __restrict__ perm,
                                                            float* acc, float* out_tail,
                                                            int nblocks) {
    int g = threadIdx.x >> 4, l = threadIdx.x & 15;
    int c = perm[blockIdx.x * 16 + g];
    uint2 sc = s2[(size_t)c * 16 + l];
    float2 c0 = bfpair(sc.x), c1 = bfpair(sc.y);
    float a = 0.0f;
    int e0 = offs[c], e1 = offs[c + 1];
    int k = e0;
    for (; k + 4 <= e1; k += 4) {
        uint4 m0 = meta[k], m1 = meta[k + 1], m2 = meta[k + 2], m3 = meta[k + 3];
        uint2 u0 = s2[(size_t)m0.x * 16 + l];
        uint2 u1 = s2[(size_t)m1.x * 16 + l];
        uint2 u2 = s2[(size_t)m2.x * 16 + l];
        uint2 u3 = s2[(size_t)m3.x * 16 + l];
        float2 p, q;
        p = bfpair(u0.x); q = bfpair(u0.y);
        a = fmaf(__uint_as_float(m0.z), p.x * c0.x + p.y * c0.y + q.x * c1.x + q.y * c1.y, a);
        p = bfpair(u1.x); q = bfpair(u1.y);
        a = fmaf(__uint_as_float(m1.z), p.x * c0.x + p.y * c0.y + q.x * c1.x + q.y * c1.y, a);
        p = bfpair(u2.x); q = bfpair(u2.y);
        a = fmaf(__uint_as_float(m2.z), p.x * c0.x + p.y * c0.y + q.x * c1.x + q.y * c1.y, a);
        p = bfpair(u3.x); q = bfpair(u3.y);
        a = fmaf(__uint_as_float(m3.z), p.x * c0.x + p.y * c0.y + q.x * c1.x + q.y * c1.y, a);
    }
    for (; k < e1; k++) {
        uint4 m0 = meta[k];
        uint2 u0 = s2[(size_t)m0.x * 16 + l];
        float2 p = bfpair(u0.x), q = bfpair(u0.y);
        a = fmaf(__uint_as_float(m0.z), p.x * c0.x + p.y * c0.y + q.x * c1.x + q.y * c1.y, a);
    }
    for (int o = 8; o; o >>= 1) a += __shfl_xor(a, o);
    __shared__ float sred[16];
    if (l == 0) sred[g] = a;
    __syncthreads();
    if (threadIdx.x == 0) {
        float s = 0.f;
#pragma unroll
        for (int j = 0; j < 16; j++) s += sred[j];
        atomicAdd(&acc[129], s);
        __threadfence();
        unsigned done = atomicAdd((unsigned*)&acc[130], 1u);
        if (done == (unsigned)(nblocks - 1)) {
            __threadfence();
            float m = acc[128] * 0.5f;
            float caca = 0.0f, cc = 0.0f;
            for (int kk = 0; kk < Cc; kk++) {
                caca += acc[64 + kk] * acc[64 + kk];
                cc += acc[kk] * acc[kk];
            }
            float tn = caca / (2.0f * m);
            float spec = -(acc[129] - tn) / (2.0f * m);
            float clust = sqrtf(cc) / (float)Nn * 8.0f - 1.0f;   // sqrt(C)=8
            out_tail[0] = 100.0f * (spec + clust);
            out_tail[1] = 100.0f * spec;
            out_tail[2] = 100.0f * clust;
        }
    }
}

extern "C" void kernel_launch(void* const* d_in, const int* in_sizes, int n_in,
                              void* d_out, int out_size, void* d_ws, size_t ws_size,
                              hipStream_t stream) {
    const void* ei = d_in[8];
    const float* ea = (const float*)d_in[1];
    const float* x  = (const float*)d_in[0];
    const float* W1 = (const float*)d_in[2];
    const float* b1 = (const float*)d_in[3];
    const float* W2 = (const float*)d_in[4];
    const float* b2 = (const float*)d_in[5];
    const float* Wm = (const float*)d_in[6];
    const float* bm = (const float*)d_in[7];
    float* out = (float*)d_out;

    size_t off = 0;
    auto carve = [&](size_t bytes) -> void* {
        void* p = (char*)d_ws + off;
        off += (bytes + 255) & ~(size_t)255;
        return p;
    };
    float*  acc    = (float*)carve(132 * 4);
    float*  deg    = (float*)carve(Nn * 4);
    float*  dinv   = (float*)carve(Nn * 4);
    float*  degrow = (float*)carve(Nn * 4);
    int*    cnt    = (int*)carve(Nn * 4);
    int*    offs   = (int*)carve((Nn + 1) * 4);
    int*    cursor = (int*)carve(Nn * 4);
    int*    perm   = (int*)carve(Nn * 4);
    int*    ebuf   = (int*)carve((size_t)2 * Ee * 4);
    uint4*  meta   = (uint4*)carve((size_t)Ee * 16);
    uint32* xb     = (uint32*)carve((size_t)Nn * 64 * 4);
    uint32* xab    = (uint32*)carve((size_t)Nn * 64 * 4);
    uint32* h1lo   = (uint32*)carve((size_t)Nn * 64 * 4);
    uint32* h1hi   = (uint32*)carve((size_t)Nn * 64 * 4);
    uint32* h1a    = (uint32*)carve((size_t)Nn * 128 * 4);
    uint32* sb     = (uint32*)carve((size_t)Nn * 32 * 4);
    ushort16* w1f  = (ushort16*)carve((size_t)4 * 16 * 64 * 8 * 2);
    ushort16* w2f  = (ushort16*)carve((size_t)8 * 16 * 64 * 8 * 2);
    ushort16* wmf  = (ushort16*)carve((size_t)8 * 4 * 64 * 8 * 2);
    int* row32 = ebuf;
    int* col32 = ebuf + Ee;

    init_kernel<<<40, 256, 0, stream>>>(deg, degrow, cnt, cursor, acc);
    bigprep_kernel<<<3181, 256, 0, stream>>>(ei, ea, x, W1, W2, Wm, xb, w1f, w2f, wmf,
                                             row32, col32, deg, degrow, cnt, acc + 128);
    scan_dinv_sort_kernel<<<1, 1024, 0, stream>>>(cnt, offs, deg, dinv, perm);
    fill_kernel<<<(Ee + 255) / 256, 256, 0, stream>>>(row32, col32, ea, dinv, offs, cursor,
                                                      meta, Ee);

    agg16_kernel<<<625, 256, 0, stream>>>((const uint4*)xb, dinv, offs, meta, perm,
                                          (uint4*)xab);
    gemm1_kernel<<<Nn / 16, 256, 0, stream>>>((const ushort16*)xab, (const short8*)w1f,
                                              b1, h1lo, h1hi);
    agg16x2_kernel<<<625, 256, 0, stream>>>((const uint4*)h1lo, (const uint4*)h1hi, dinv,
                                            offs, meta, perm, (uint4*)h1a);
    gemm2_softmax_kernel<<<Nn / 16, 256, 0, stream>>>((const ushort16*)h1a,
                                                      (const short8*)w2f, b2,
                                                      (const short8*)wmf, bm, degrow,
                                                      out, sb, acc);
    trace16_final_kernel<<<625, 256, 0, stream>>>(offs, meta, (const uint2*)sb, perm, acc,
                                                  out + (size_t)Nn * Cc, 625);
}

// Round 15
// 199.513 us; speedup vs baseline: 1.0934x; 1.0934x over previous
//
#include <hip/hip_runtime.h>
#include <hip/hip_bf16.h>

#define Nn 10000
#define Ee 160000
#define Hid 256
#define Cc 64

typedef unsigned int uint32;
typedef unsigned short ushort16;
typedef __attribute__((ext_vector_type(8))) short short8;
typedef __attribute__((ext_vector_type(4))) float float4v;

__device__ inline float2 bfpair(uint32 u) {
    float2 r;
    r.x = __uint_as_float(u << 16);
    r.y = __uint_as_float(u & 0xffff0000u);
    return r;
}
__device__ inline ushort16 f2bf(float f) {
    __hip_bfloat16 h = __float2bfloat16(f);
    union { __hip_bfloat16 h; ushort16 u; } cv;
    cv.h = h;
    return cv.u;
}
__device__ inline uint32 packbf(float a, float b) {
    return (uint32)f2bf(a) | ((uint32)f2bf(b) << 16);
}

// ---- init: node arrays + acc (MUST complete before any atomics) ----------------
__global__ __launch_bounds__(256) void init_kernel(float* deg, float* degrow,
                                                   int* cnt, int* cursor, float* acc) {
    int i = blockIdx.x * 256 + threadIdx.x;
    if (i < Nn) { deg[i] = 1.0f; degrow[i] = 0.0f; cnt[i] = 0; cursor[i] = 0; }
    if (blockIdx.x == 0 && threadIdx.x < 132) acc[threadIdx.x] = 0.0f;
}

// ---- bigprep: x->bf16 + W fragments + edge convert/stats (after init) ----------
// blocks 0..2499: x. 2500..2515: W1. 2516..2547: W2. 2548..2555: Wm. 2556..3180: edges.
__global__ __launch_bounds__(256) void bigprep_kernel(const void* ei,
                                                      const float* __restrict__ ea,
                                                      const float* __restrict__ x,
                                                      const float* __restrict__ W1,
                                                      const float* __restrict__ W2,
                                                      const float* __restrict__ Wm,
                                                      uint32* __restrict__ xb,
                                                      ushort16* __restrict__ w1f,
                                                      ushort16* __restrict__ w2f,
                                                      ushort16* __restrict__ wmf,
                                                      int* row32, int* col32,
                                                      float* deg, float* degrow,
                                                      int* cnt, float* g_sum_ea) {
    int b = blockIdx.x, t = threadIdx.x;
    if (b < 2500) {                                     // x: 640000 bf16 pairs
        int i = b * 256 + t;
        float2 v = *(const float2*)(x + 2 * (size_t)i);
        xb[i] = packbf(v.x, v.y);
    } else if (b < 2516) {                              // W1 frags: KT=4, NT=16
        int idx = (b - 2500) * 256 + t;
        int l = idx & 63, nt = (idx >> 6) & 15, kt = idx >> 10;
        int k0 = kt * 32 + (l >> 4) * 8, c = nt * 16 + (l & 15);
#pragma unroll
        for (int j = 0; j < 8; j++) w1f[idx * 8 + j] = f2bf(W1[(size_t)(k0 + j) * Hid + c]);
    } else if (b < 2548) {                              // W2 frags: KT=8, NT=16
        int idx = (b - 2516) * 256 + t;
        int l = idx & 63, nt = (idx >> 6) & 15, kt = idx >> 10;
        int k0 = kt * 32 + (l >> 4) * 8, c = nt * 16 + (l & 15);
#pragma unroll
        for (int j = 0; j < 8; j++) w2f[idx * 8 + j] = f2bf(W2[(size_t)(k0 + j) * Hid + c]);
    } else if (b < 2556) {                              // Wm frags: KT=8, NT=4
        int idx = (b - 2548) * 256 + t;
        int l = idx & 63, nt = (idx >> 6) & 3, kt = idx >> 8;
        int k0 = kt * 32 + (l >> 4) * 8, c = nt * 16 + (l & 15);
#pragma unroll
        for (int j = 0; j < 8; j++) wmf[idx * 8 + j] = f2bf(Wm[(size_t)(k0 + j) * Cc + c]);
    } else {                                            // edges: convert + stats
        __shared__ int any;
        if (t == 0) any = 0;
        __syncthreads();
        const int* w = (const int*)ei;
        for (int j = t; j < 1024; j += 256)
            if (w[2 * j + 1] != 0) { atomicOr(&any, 1); break; }
        __syncthreads();
        int is64 = (any == 0);
        int e = (b - 2556) * 256 + t;
        float v = 0.0f;
        if (e < Ee) {
            int r, c;
            if (is64) {
                r = (int)((const long long*)ei)[e];
                c = (int)((const long long*)ei)[Ee + e];
            } else {
                r = ((const int*)ei)[e];
                c = ((const int*)ei)[Ee + e];
            }
            row32[e] = r;
            col32[e] = c;
            float wv = ea[e];
            v = wv;
            atomicAdd(&deg[c], wv);
            atomicAdd(&degrow[r], wv);
            atomicAdd(&cnt[c], 1);
        }
        for (int o = 32; o; o >>= 1) v += __shfl_xor(v, o);
        __shared__ float sred[4];
        if ((t & 63) == 0) sred[t >> 6] = v;
        __syncthreads();
        if (t == 0) atomicAdd(g_sum_ea, sred[0] + sred[1] + sred[2] + sred[3]);
    }
}

// ---- one-pass scan: thread owns 10 nodes, single block-scan + dinv -------------
__global__ __launch_bounds__(1024) void scan_dinv_kernel(const int* cnt, int* offs,
                                                         const float* deg, float* dinv) {
    int t = threadIdx.x;
    for (int i = t; i < Nn; i += 1024) dinv[i] = rsqrtf(deg[i]);
    int st = t * 10;
    int pre[10];
    int s = 0;
#pragma unroll
    for (int j = 0; j < 10; j++) {
        int i = st + j;
        int v = (i < Nn) ? cnt[i] : 0;
        pre[j] = s;
        s += v;
    }
    int lane = t & 63, w = t >> 6;
    __shared__ int wsum[16];
    int ps = s;
    for (int d = 1; d < 64; d <<= 1) {
        int u = __shfl_up(ps, d);
        if (lane >= d) ps += u;
    }
    if (lane == 63) wsum[w] = ps;
    __syncthreads();
    if (w == 0 && lane < 16) {
        int v = wsum[lane];
        for (int d = 1; d < 16; d <<= 1) {
            int u = __shfl_up(v, d);
            if (lane >= d) v += u;
        }
        wsum[lane] = v;
    }
    __syncthreads();
    int base = (w > 0 ? wsum[w - 1] : 0) + ps - s;
#pragma unroll
    for (int j = 0; j < 10; j++) {
        int i = st + j;
        if (i < Nn) offs[i] = base + pre[j];
    }
    if (t == 1023) offs[Nn] = wsum[15];
}

// ---------------- fill CSC as 16B records {r, norm, ea, 0} ----------------------
__global__ __launch_bounds__(256) void fill_kernel(const int* __restrict__ row,
                                                   const int* __restrict__ col,
                                                   const float* __restrict__ ew,
                                                   const float* __restrict__ dinv,
                                                   const int* __restrict__ offs, int* cursor,
                                                   uint4* __restrict__ meta, int E) {
    int e = blockIdx.x * 256 + threadIdx.x;
    if (e >= E) return;
    int r = row[e], c = col[e];
    int slot = offs[c] + atomicAdd(&cursor[c], 1);
    float w = ew[e];
    uint4 m;
    m.x = (uint32)r;
    m.y = __float_as_uint(dinv[r] * w * dinv[c]);
    m.z = __float_as_uint(w);
    m.w = 0;
    meta[slot] = m;
}

// ---- agg single plane: 16 lanes/node, uint4 gathers (layer 1) ------------------
__global__ __launch_bounds__(256) void agg16_kernel(const uint4* __restrict__ src,
                                                    const float* __restrict__ dinv,
                                                    const int* __restrict__ offs,
                                                    const uint4* __restrict__ meta,
                                                    uint4* __restrict__ dst) {
    int g = threadIdx.x >> 4, l = threadIdx.x & 15;
    int i = blockIdx.x * 16 + g;
    float di = dinv[i];
    float w2 = di * di;
    uint4 su = src[(size_t)i * 16 + l];
    float a0, a1, a2, a3, a4, a5, a6, a7;
    {
        float2 p0 = bfpair(su.x), p1 = bfpair(su.y), p2 = bfpair(su.z), p3 = bfpair(su.w);
        a0 = w2 * p0.x; a1 = w2 * p0.y; a2 = w2 * p1.x; a3 = w2 * p1.y;
        a4 = w2 * p2.x; a5 = w2 * p2.y; a6 = w2 * p3.x; a7 = w2 * p3.y;
    }
#define ACC8(u, wgt) { \
        float2 p0 = bfpair(u.x), p1 = bfpair(u.y), p2 = bfpair(u.z), p3 = bfpair(u.w); \
        a0 = fmaf(wgt, p0.x, a0); a1 = fmaf(wgt, p0.y, a1); \
        a2 = fmaf(wgt, p1.x, a2); a3 = fmaf(wgt, p1.y, a3); \
        a4 = fmaf(wgt, p2.x, a4); a5 = fmaf(wgt, p2.y, a5); \
        a6 = fmaf(wgt, p3.x, a6); a7 = fmaf(wgt, p3.y, a7); }
    int e0 = offs[i], e1 = offs[i + 1];
    int k = e0;
    for (; k + 4 <= e1; k += 4) {
        uint4 m0 = meta[k], m1 = meta[k + 1], m2 = meta[k + 2], m3 = meta[k + 3];
        uint4 u0 = src[(size_t)m0.x * 16 + l];
        uint4 u1 = src[(size_t)m1.x * 16 + l];
        uint4 u2 = src[(size_t)m2.x * 16 + l];
        uint4 u3 = src[(size_t)m3.x * 16 + l];
        ACC8(u0, __uint_as_float(m0.y));
        ACC8(u1, __uint_as_float(m1.y));
        ACC8(u2, __uint_as_float(m2.y));
        ACC8(u3, __uint_as_float(m3.y));
    }
    for (; k < e1; k++) {
        uint4 m0 = meta[k];
        uint4 u0 = src[(size_t)m0.x * 16 + l];
        ACC8(u0, __uint_as_float(m0.y));
    }
#undef ACC8
    uint4 o;
    o.x = packbf(a0, a1);
    o.y = packbf(a2, a3);
    o.z = packbf(a4, a5);
    o.w = packbf(a6, a7);
    dst[(size_t)i * 16 + l] = o;
}

// ---- agg DUAL plane (layer 2): one meta read, 8 gathers in flight --------------
__global__ __launch_bounds__(256) void agg16x2_kernel(const uint4* __restrict__ srcLo,
                                                      const uint4* __restrict__ srcHi,
                                                      const float* __restrict__ dinv,
                                                      const int* __restrict__ offs,
                                                      const uint4* __restrict__ meta,
                                                      uint4* __restrict__ dst) {
    int g = threadIdx.x >> 4, l = threadIdx.x & 15;
    int i = blockIdx.x * 16 + g;
    float di = dinv[i];
    float w2 = di * di;
    uint4 slo = srcLo[(size_t)i * 16 + l];
    uint4 shi = srcHi[(size_t)i * 16 + l];
    float a0, a1, a2, a3, a4, a5, a6, a7;
    float b0, b1, b2, b3, b4, b5, b6, b7;
    {
        float2 p0 = bfpair(slo.x), p1 = bfpair(slo.y), p2 = bfpair(slo.z), p3 = bfpair(slo.w);
        a0 = w2 * p0.x; a1 = w2 * p0.y; a2 = w2 * p1.x; a3 = w2 * p1.y;
        a4 = w2 * p2.x; a5 = w2 * p2.y; a6 = w2 * p3.x; a7 = w2 * p3.y;
        float2 q0 = bfpair(shi.x), q1 = bfpair(shi.y), q2 = bfpair(shi.z), q3 = bfpair(shi.w);
        b0 = w2 * q0.x; b1 = w2 * q0.y; b2 = w2 * q1.x; b3 = w2 * q1.y;
        b4 = w2 * q2.x; b5 = w2 * q2.y; b6 = w2 * q3.x; b7 = w2 * q3.y;
    }
#define ACCLO(u, wgt) { \
        float2 p0 = bfpair(u.x), p1 = bfpair(u.y), p2 = bfpair(u.z), p3 = bfpair(u.w); \
        a0 = fmaf(wgt, p0.x, a0); a1 = fmaf(wgt, p0.y, a1); \
        a2 = fmaf(wgt, p1.x, a2); a3 = fmaf(wgt, p1.y, a3); \
        a4 = fmaf(wgt, p2.x, a4); a5 = fmaf(wgt, p2.y, a5); \
        a6 = fmaf(wgt, p3.x, a6); a7 = fmaf(wgt, p3.y, a7); }
#define ACCHI(u, wgt) { \
        float2 p0 = bfpair(u.x), p1 = bfpair(u.y), p2 = bfpair(u.z), p3 = bfpair(u.w); \
        b0 = fmaf(wgt, p0.x, b0); b1 = fmaf(wgt, p0.y, b1); \
        b2 = fmaf(wgt, p1.x, b2); b3 = fmaf(wgt, p1.y, b3); \
        b4 = fmaf(wgt, p2.x, b4); b5 = fmaf(wgt, p2.y, b5); \
        b6 = fmaf(wgt, p3.x, b6); b7 = fmaf(wgt, p3.y, b7); }
    int e0 = offs[i], e1 = offs[i + 1];
    int k = e0;
    for (; k + 4 <= e1; k += 4) {
        uint4 m0 = meta[k], m1 = meta[k + 1], m2 = meta[k + 2], m3 = meta[k + 3];
        uint4 lo0 = srcLo[(size_t)m0.x * 16 + l];
        uint4 lo1 = srcLo[(size_t)m1.x * 16 + l];
        uint4 lo2 = srcLo[(size_t)m2.x * 16 + l];
        uint4 lo3 = srcLo[(size_t)m3.x * 16 + l];
        uint4 hi0 = srcHi[(size_t)m0.x * 16 + l];
        uint4 hi1 = srcHi[(size_t)m1.x * 16 + l];
        uint4 hi2 = srcHi[(size_t)m2.x * 16 + l];
        uint4 hi3 = srcHi[(size_t)m3.x * 16 + l];
        float w0 = __uint_as_float(m0.y), w1 = __uint_as_float(m1.y);
        float w2_ = __uint_as_float(m2.y), w3 = __uint_as_float(m3.y);
        ACCLO(lo0, w0); ACCHI(hi0, w0);
        ACCLO(lo1, w1); ACCHI(hi1, w1);
        ACCLO(lo2, w2_); ACCHI(hi2, w2_);
        ACCLO(lo3, w3); ACCHI(hi3, w3);
    }
    for (; k < e1; k++) {
        uint4 m0 = meta[k];
        uint4 lo0 = srcLo[(size_t)m0.x * 16 + l];
        uint4 hi0 = srcHi[(size_t)m0.x * 16 + l];
        float w0 = __uint_as_float(m0.y);
        ACCLO(lo0, w0); ACCHI(hi0, w0);
    }
#undef ACCLO
#undef ACCHI
    uint4 o;
    o.x = packbf(a0, a1);
    o.y = packbf(a2, a3);
    o.z = packbf(a4, a5);
    o.w = packbf(a6, a7);
    dst[(size_t)i * 32 + l] = o;
    o.x = packbf(b0, b1);
    o.y = packbf(b2, b3);
    o.z = packbf(b4, b5);
    o.w = packbf(b6, b7);
    dst[(size_t)i * 32 + 16 + l] = o;
}

// ---------------- gemm1: C = relu(A[M,128]bf16 @ W1 + b1) -> two planes ---------
__global__ __launch_bounds__(256) void gemm1_kernel(const ushort16* __restrict__ A,
                                                    const short8* __restrict__ wfrag,
                                                    const float* __restrict__ bias,
                                                    uint32* __restrict__ Plo,
                                                    uint32* __restrict__ Phi) {
    constexpr int KT = 4;
    int wave = threadIdx.x >> 6, lane = threadIdx.x & 63;
    int quad = lane >> 4, l4 = lane & 15;
    int rowbase = blockIdx.x * 16;
    int n0 = wave * 4;
    float4v acc[4];
#pragma unroll
    for (int n = 0; n < 4; n++) acc[n] = (float4v){0.f, 0.f, 0.f, 0.f};
    const short8* arow = (const short8*)(A + (size_t)(rowbase + l4) * 128 + quad * 8);
#pragma unroll
    for (int t = 0; t < KT; t++) {
        short8 a = arow[t * 4];
        const short8* bt = wfrag + ((size_t)t * 16 + n0) * 64 + lane;
#pragma unroll
        for (int n = 0; n < 4; n++)
            acc[n] = __builtin_amdgcn_mfma_f32_16x16x32_bf16(a, bt[n * 64], acc[n], 0, 0, 0);
    }
#pragma unroll
    for (int n = 0; n < 4; n++) {
        int col = (n0 + n) * 16 + l4;
        float bv = bias[col];
#pragma unroll
        for (int r = 0; r < 4; r++) {
            float v = fmaxf(acc[n][r] + bv, 0.0f);
            float v2 = __shfl_xor(v, 1);
            if ((l4 & 1) == 0) {
                int rowi = rowbase + quad * 4 + r;
                int pi = col >> 1;
                uint32 val = packbf(v, v2);
                uint32* P = (pi < 64) ? Plo : Phi;
                P[(size_t)rowi * 64 + (pi & 63)] = val;
            }
        }
    }
}

// ---- fused gemm2 + softmax: h2 tile stays in LDS; logits K-split across waves --
__global__ __launch_bounds__(256) void gemm2_softmax_kernel(
    const ushort16* __restrict__ A,          // h1a [Nn,256] bf16
    const short8* __restrict__ w2f,          // KT=8, NT=16
    const float* __restrict__ b2,
    const short8* __restrict__ wmf,          // KT=8, NT=4
    const float* __restrict__ bm,
    const float* __restrict__ degrow,
    float* __restrict__ s_out,
    uint32* __restrict__ sb,
    float* __restrict__ acc) {
    __shared__ uint32 h2s[16][132];          // bf16 pairs, padded (bank decorrelation)
    __shared__ float Lw[4][16][65];          // per-wave logit slabs, padded
    int t = threadIdx.x;
    int wave = t >> 6, lane = t & 63;
    int quad = lane >> 4, l4 = lane & 15;
    int rowbase = blockIdx.x * 16;

    // ---- phase A: gemm2 tile -> LDS ---------------------------------------------
    float4v acc4[4];
#pragma unroll
    for (int n = 0; n < 4; n++) acc4[n] = (float4v){0.f, 0.f, 0.f, 0.f};
    const short8* arow = (const short8*)(A + (size_t)(rowbase + l4) * Hid + quad * 8);
#pragma unroll
    for (int tt = 0; tt < 8; tt++) {
        short8 a = arow[tt * 4];
        const short8* bt = w2f + ((size_t)tt * 16 + wave * 4) * 64 + lane;
#pragma unroll
        for (int n = 0; n < 4; n++)
            acc4[n] = __builtin_amdgcn_mfma_f32_16x16x32_bf16(a, bt[n * 64], acc4[n], 0, 0, 0);
    }
#pragma unroll
    for (int n = 0; n < 4; n++) {
        int col = (wave * 4 + n) * 16 + l4;
        float bv = b2[col];
#pragma unroll
        for (int r = 0; r < 4; r++) {
            float v = fmaxf(acc4[n][r] + bv, 0.0f);
            float v2 = __shfl_xor(v, 1);
            if ((l4 & 1) == 0) h2s[quad * 4 + r][col >> 1] = packbf(v, v2);
        }
    }
    __syncthreads();

    // ---- phase B: logits partial, wave w handles ktiles 2w, 2w+1 ----------------
    float4v lg[4];
#pragma unroll
    for (int n = 0; n < 4; n++) lg[n] = (float4v){0.f, 0.f, 0.f, 0.f};
#pragma unroll
    for (int tt = 0; tt < 2; tt++) {
        int kt = wave * 2 + tt;
        short8 a = *(const short8*)&h2s[l4][kt * 16 + quad * 4];
        const short8* bt = wmf + ((size_t)kt * 4) * 64 + lane;
#pragma unroll
        for (int n = 0; n < 4; n++)
            lg[n] = __builtin_amdgcn_mfma_f32_16x16x32_bf16(a, bt[n * 64], lg[n], 0, 0, 0);
    }
#pragma unroll
    for (int n = 0; n < 4; n++)
#pragma unroll
        for (int r = 0; r < 4; r++)
            Lw[wave][quad * 4 + r][n * 16 + l4] = lg[n][r];
    __syncthreads();

    // ---- phase C: wave 0 does softmax over 16 rows x 64 cols --------------------
    if (wave == 0) {
        float pc = 0.0f, pa = 0.0f;
        for (int r = 0; r < 16; r++) {
            float v = bm[lane] + Lw[0][r][lane] + Lw[1][r][lane] + Lw[2][r][lane]
                    + Lw[3][r][lane];
            float mx = v;
            for (int o = 32; o; o >>= 1) mx = fmaxf(mx, __shfl_xor(mx, o));
            float e = __expf(v - mx);
            float ss = e;
            for (int o = 32; o; o >>= 1) ss += __shfl_xor(ss, o);
            float sv = e / ss;
            int rowi = rowbase + r;
            s_out[(size_t)rowi * Cc + lane] = sv;
            float sv2 = __shfl_xor(sv, 1);
            if ((lane & 1) == 0) sb[(size_t)rowi * 32 + (lane >> 1)] = packbf(sv, sv2);
            pc += sv;
            pa += sv * degrow[rowi];
        }
        atomicAdd(&acc[lane], pc);
        atomicAdd(&acc[64 + lane], pa);
    }
}

// ---------------- trace via CSC: 16 lanes/col, uint2 gathers --------------------
__global__ __launch_bounds__(256) void trace16_kernel(const int* __restrict__ offs,
                                                      const uint4* __restrict__ meta,
                                                      const uint2* __restrict__ s2,
                                                      float* g_trace) {
    int g = threadIdx.x >> 4, l = threadIdx.x & 15;
    int c = blockIdx.x * 16 + g;
    uint2 sc = s2[(size_t)c * 16 + l];
    float2 c0 = bfpair(sc.x), c1 = bfpair(sc.y);
    float a = 0.0f;
    int e0 = offs[c], e1 = offs[c + 1];
    int k = e0;
    for (; k + 4 <= e1; k += 4) {
        uint4 m0 = meta[k], m1 = meta[k + 1], m2 = meta[k + 2], m3 = meta[k + 3];
        uint2 u0 = s2[(size_t)m0.x * 16 + l];
        uint2 u1 = s2[(size_t)m1.x * 16 + l];
        uint2 u2 = s2[(size_t)m2.x * 16 + l];
        uint2 u3 = s2[(size_t)m3.x * 16 + l];
        float2 p, q;
        p = bfpair(u0.x); q = bfpair(u0.y);
        a = fmaf(__uint_as_float(m0.z), p.x * c0.x + p.y * c0.y + q.x * c1.x + q.y * c1.y, a);
        p = bfpair(u1.x); q = bfpair(u1.y);
        a = fmaf(__uint_as_float(m1.z), p.x * c0.x + p.y * c0.y + q.x * c1.x + q.y * c1.y, a);
        p = bfpair(u2.x); q = bfpair(u2.y);
        a = fmaf(__uint_as_float(m2.z), p.x * c0.x + p.y * c0.y + q.x * c1.x + q.y * c1.y, a);
        p = bfpair(u3.x); q = bfpair(u3.y);
        a = fmaf(__uint_as_float(m3.z), p.x * c0.x + p.y * c0.y + q.x * c1.x + q.y * c1.y, a);
    }
    for (; k < e1; k++) {
        uint4 m0 = meta[k];
        uint2 u0 = s2[(size_t)m0.x * 16 + l];
        float2 p = bfpair(u0.x), q = bfpair(u0.y);
        a = fmaf(__uint_as_float(m0.z), p.x * c0.x + p.y * c0.y + q.x * c1.x + q.y * c1.y, a);
    }
    for (int o = 8; o; o >>= 1) a += __shfl_xor(a, o);
    __shared__ float sred[16];
    if (l == 0) sred[g] = a;
    __syncthreads();
    if (threadIdx.x == 0) {
        float s = 0.f;
#pragma unroll
        for (int j = 0; j < 16; j++) s += sred[j];
        atomicAdd(g_trace, s);
    }
}

// ---------------- final scalars -------------------------------------------------
__global__ void final_kernel(const float* acc, float* out_tail) {
    float m = acc[128] * 0.5f;
    float caca = 0.0f, cc = 0.0f;
    for (int k = 0; k < Cc; k++) {
        caca += acc[64 + k] * acc[64 + k];
        cc += acc[k] * acc[k];
    }
    float tn = caca / (2.0f * m);
    float spec = -(acc[129] - tn) / (2.0f * m);
    float clust = sqrtf(cc) / (float)Nn * 8.0f - 1.0f;   // sqrt(C)=8
    out_tail[0] = 100.0f * (spec + clust);
    out_tail[1] = 100.0f * spec;
    out_tail[2] = 100.0f * clust;
}

extern "C" void kernel_launch(void* const* d_in, const int* in_sizes, int n_in,
                              void* d_out, int out_size, void* d_ws, size_t ws_size,
                              hipStream_t stream) {
    const void* ei = d_in[8];
    const float* ea = (const float*)d_in[1];
    const float* x  = (const float*)d_in[0];
    const float* W1 = (const float*)d_in[2];
    const float* b1 = (const float*)d_in[3];
    const float* W2 = (const float*)d_in[4];
    const float* b2 = (const float*)d_in[5];
    const float* Wm = (const float*)d_in[6];
    const float* bm = (const float*)d_in[7];
    float* out = (float*)d_out;

    size_t off = 0;
    auto carve = [&](size_t bytes) -> void* {
        void* p = (char*)d_ws + off;
        off += (bytes + 255) & ~(size_t)255;
        return p;
    };
    float*  acc    = (float*)carve(132 * 4);
    float*  deg    = (float*)carve(Nn * 4);
    float*  dinv   = (float*)carve(Nn * 4);
    float*  degrow = (float*)carve(Nn * 4);
    int*    cnt    = (int*)carve(Nn * 4);
    int*    offs   = (int*)carve((Nn + 1) * 4);
    int*    cursor = (int*)carve(Nn * 4);
    int*    ebuf   = (int*)carve((size_t)2 * Ee * 4);
    uint4*  meta   = (uint4*)carve((size_t)Ee * 16);         // {r, norm, ea, 0}
    uint32* xb     = (uint32*)carve((size_t)Nn * 64 * 4);    // x bf16
    uint32* xab    = (uint32*)carve((size_t)Nn * 64 * 4);    // agg(x) bf16
    uint32* h1lo   = (uint32*)carve((size_t)Nn * 64 * 4);    // h1 cols 0..127
    uint32* h1hi   = (uint32*)carve((size_t)Nn * 64 * 4);    // h1 cols 128..255
    uint32* h1a    = (uint32*)carve((size_t)Nn * 128 * 4);   // agg(h1) contiguous
    uint32* sb     = (uint32*)carve((size_t)Nn * 32 * 4);    // s bf16
    ushort16* w1f  = (ushort16*)carve((size_t)4 * 16 * 64 * 8 * 2);
    ushort16* w2f  = (ushort16*)carve((size_t)8 * 16 * 64 * 8 * 2);
    ushort16* wmf  = (ushort16*)carve((size_t)8 * 4 * 64 * 8 * 2);
    int* row32 = ebuf;
    int* col32 = ebuf + Ee;

    init_kernel<<<40, 256, 0, stream>>>(deg, degrow, cnt, cursor, acc);
    bigprep_kernel<<<3181, 256, 0, stream>>>(ei, ea, x, W1, W2, Wm, xb, w1f, w2f, wmf,
                                             row32, col32, deg, degrow, cnt, acc + 128);
    scan_dinv_kernel<<<1, 1024, 0, stream>>>(cnt, offs, deg, dinv);
    fill_kernel<<<(Ee + 255) / 256, 256, 0, stream>>>(row32, col32, ea, dinv, offs, cursor,
                                                      meta, Ee);

    // layer 1
    agg16_kernel<<<625, 256, 0, stream>>>((const uint4*)xb, dinv, offs, meta, (uint4*)xab);
    gemm1_kernel<<<Nn / 16, 256, 0, stream>>>((const ushort16*)xab, (const short8*)w1f,
                                              b1, h1lo, h1hi);
    // layer 2 + fused softmax
    agg16x2_kernel<<<625, 256, 0, stream>>>((const uint4*)h1lo, (const uint4*)h1hi, dinv,
                                            offs, meta, (uint4*)h1a);
    gemm2_softmax_kernel<<<Nn / 16, 256, 0, stream>>>((const ushort16*)h1a,
                                                      (const short8*)w2f, b2,
                                                      (const short8*)wmf, bm, degrow,
                                                      out, sb, acc);

    trace16_kernel<<<625, 256, 0, stream>>>(offs, meta, (const uint2*)sb, acc + 129);
    final_kernel<<<1, 1, 0, stream>>>(acc, out + (size_t)Nn * Cc);
}